// Round 3
// baseline (455.166 us; speedup 1.0000x reference)
//
#include <hip/hip_runtime.h>
#include <cstdio>
#include <cstdint>

typedef _Float16 h8 __attribute__((ext_vector_type(8)));
typedef _Float16 h4 __attribute__((ext_vector_type(4)));
typedef _Float16 h2 __attribute__((ext_vector_type(2)));
typedef float f4 __attribute__((ext_vector_type(4)));

#define GLD16(g, l) __builtin_amdgcn_global_load_lds( \
    (const __attribute__((address_space(1))) void*)(g), \
    (__attribute__((address_space(3))) void*)(l), 16, 0, 0)

static constexpr int HOUT = 28;
static constexpr long long NSP = 64LL * HOUT * HOUT;     // 50176 output pixels
static constexpr long long NEL = NSP * 256;              // 12,845,056 output elems
static constexpr int NSLOT = 64;                         // spread atomic slots
static constexpr int SLOTSTRIDE = 32;                    // 128B apart

// ---------------------------------------------------------------------------
__global__ void init_ws(int* __restrict__ slots, _Float16* __restrict__ zp)
{
    const int t = threadIdx.x;
    for (int i = t; i < 3 * NSLOT * SLOTSTRIDE; i += 256) slots[i] = 0;
    for (int i = t; i < 512; i += 256) zp[i] = (_Float16)0.f;
}

__device__ __forceinline__ float slot_max(const int* __restrict__ slots)
{
    float m = 0.f;
#pragma unroll
    for (int i = 0; i < NSLOT; ++i) m = fmaxf(m, __int_as_float(slots[i * SLOTSTRIDE]));
    return m;
}

// ---------------------------------------------------------------------------
// weight prep: per-output-channel symmetric 8-bit quant, BN fold, k-reorder.
// conv1 weights channel-DUPLICATED (k = p*256 + cc, cc=ci or ci+128) to match
// the hi/lo split input.
__global__ void prep_w1(const float* __restrict__ w1, const float* __restrict__ g1,
                        const float* __restrict__ b1, const float* __restrict__ m1,
                        const float* __restrict__ v1, const float* __restrict__ asp,
                        _Float16* __restrict__ wq, float* __restrict__ scale1,
                        float* __restrict__ bias1)
{
    const int o = blockIdx.x, t = threadIdx.x;
    const float f = g1[o] * rsqrtf(v1[o] + 1e-5f);
    const float* wr = w1 + (size_t)o * 1152;
    float amax = 0.f;
    for (int i = t; i < 1152; i += 256) amax = fmaxf(amax, fabsf(wr[i] * f));
    __shared__ float red[256];
    red[t] = amax; __syncthreads();
    for (int s = 128; s > 0; s >>= 1) { if (t < s) red[t] = fmaxf(red[t], red[t + s]); __syncthreads(); }
    const float ws = fmaxf(red[0] / 127.f, 1e-8f);
    for (int idx = t; idx < 2304; idx += 256) {
        int p = idx >> 8, cc = idx & 255, ci = cc & 127;
        float q = fminf(fmaxf(rintf(wr[ci * 9 + p] * f / ws), -128.f), 127.f);
        wq[(size_t)o * 2304 + idx] = (_Float16)q;
    }
    if (t == 0) {
        const float bs = ws * asp[0];
        const float bf = b1[o] - m1[o] * f;
        float bq = fminf(fmaxf(rintf(bf / bs), -128.f), 127.f);
        scale1[o] = bs;
        bias1[o] = bq * bs;
    }
}

__global__ void prep_w2(const float* __restrict__ w2, const float* __restrict__ g2,
                        const float* __restrict__ b2, const float* __restrict__ m2,
                        const float* __restrict__ v2,
                        _Float16* __restrict__ wq, float* __restrict__ ws2,
                        float* __restrict__ b2f)
{
    const int o = blockIdx.x, t = threadIdx.x;
    const float f = g2[o] * rsqrtf(v2[o] + 1e-5f);
    const float* wr = w2 + (size_t)o * 2304;
    float amax = 0.f;
    for (int i = t; i < 2304; i += 256) amax = fmaxf(amax, fabsf(wr[i] * f));
    __shared__ float red[256];
    red[t] = amax; __syncthreads();
    for (int s = 128; s > 0; s >>= 1) { if (t < s) red[t] = fmaxf(red[t], red[t + s]); __syncthreads(); }
    const float ws = fmaxf(red[0] / 127.f, 1e-8f);
    for (int idx = t; idx < 2304; idx += 256) {
        int p = idx >> 8, ci = idx & 255;
        float q = fminf(fmaxf(rintf(wr[ci * 9 + p] * f / ws), -128.f), 127.f);
        wq[(size_t)o * 2304 + idx] = (_Float16)q;
    }
    if (t == 0) { ws2[o] = ws; b2f[o] = b2[o] - m2[o] * f; }
}

__global__ void prep_wsc(const float* __restrict__ wsc, const float* __restrict__ asp,
                         _Float16* __restrict__ wq, float* __restrict__ scale_sc)
{
    const int o = blockIdx.x, t = threadIdx.x;
    const float* wr = wsc + (size_t)o * 128;
    float amax = (t < 128) ? fabsf(wr[t]) : 0.f;
    __shared__ float red[256];
    red[t] = amax; __syncthreads();
    for (int s = 128; s > 0; s >>= 1) { if (t < s) red[t] = fmaxf(red[t], red[t + s]); __syncthreads(); }
    const float ws = fmaxf(red[0] / 127.f, 1e-8f);
    float q = fminf(fmaxf(rintf(wr[t & 127] / ws), -128.f), 127.f);
    wq[(size_t)o * 256 + t] = (_Float16)q;   // duplicated layout [o][256]
    if (t == 0) scale_sc[o] = ws * asp[0];
}

// ---------------------------------------------------------------------------
// x (NCHW f32) -> column-parity NHWC fp16 hi/lo pairs of x/act_scale.
// layout: xf[b][ih][par][j][256] where iw = 2*j + par. one block per (b,h).
__global__ void prep_x(const float* __restrict__ x, const float* __restrict__ asp,
                       _Float16* __restrict__ xf)
{
    const int b = blockIdx.x / 56, h = blockIdx.x - (blockIdx.x / 56) * 56;
    const float as = asp[0];
    __shared__ float tile[56 * 129];
    const float* src = x + ((size_t)b * 128 * 56 + h) * 56;   // x[b][c][h][w]
    for (int i = threadIdx.x; i < 7168; i += 256) {
        int c = i / 56, ww = i - c * 56;
        tile[ww * 129 + c] = src[(size_t)c * 3136 + ww] / as;
    }
    __syncthreads();
    _Float16* dst = xf + (size_t)(b * 56 + h) * 2 * 28 * 256;
    for (int j = threadIdx.x; j < 7168; j += 256) {
        int ww = j >> 7, q = j & 127;
        int cc = q * 2;
        int c0 = cc & 127, c1 = (cc + 1) & 127;
        float x0 = tile[ww * 129 + c0];
        float x1 = tile[ww * 129 + c1];
        h2 o;
        if (cc < 128) { o[0] = (_Float16)x0; o[1] = (_Float16)x1; }
        else {
            _Float16 h0 = (_Float16)x0, h1 = (_Float16)x1;
            o[0] = (_Float16)(x0 - (float)h0);
            o[1] = (_Float16)(x1 - (float)h1);
        }
        size_t eo = ((size_t)(ww & 1) * 28 + (ww >> 1)) * 256 + (size_t)cc;
        *(h2*)&dst[eo] = o;
    }
}

// ---------------------------------------------------------------------------
// pipelined implicit-GEMM conv: BM=BN=128, BK=32, 4 waves, f16 MFMA.
// 2-phase software pipeline: stage(ks+1) issued before compute(ks), raw
// s_barrier + counted vmcnt(4) so next-step loads stay in flight.
// LDS is fragment-major (each b128 sub-tile read = 64 lanes contiguous 1KB,
// conflict-free); realized by permuting the global SOURCE per lane (m173).
// MODE 0: conv1 3x3 s2 (parity xf), MODE 1: conv2 3x3 s1, MODE 2: 1x1 s2.
template<int MODE>
__global__ __launch_bounds__(256, 3)
void conv_k(const _Float16* __restrict__ Xf,
            const _Float16* __restrict__ Wq,
            const float* __restrict__ scale,
            const float* __restrict__ bias,
            float* __restrict__ Y,               // [N][256]
            int* __restrict__ slots,
            const _Float16* __restrict__ zp)
{
    constexpr int KT = (MODE == 2) ? 256 : 2304;
    constexpr int NSTEP = KT / 32;
    __shared__ __attribute__((aligned(16))) _Float16 As[2][4096];
    __shared__ __attribute__((aligned(16))) _Float16 Bs[2][4096];
    __shared__ float wred[4];

    const int t = threadIdx.x;
    const int wave = t >> 6, lane = t & 63;
    const int wm = wave >> 1, wn = wave & 1;
    const int fr = lane & 15, fq = lane >> 4;

    // bijective XCD-chunked swizzle over 784 blocks (8 XCDs x 98);
    // m-pair adjacent so both m-tiles of an n-tile share an XCD's L2.
    const int id = blockIdx.x;
    const int lin = (id & 7) * 98 + (id >> 3);
    const int m0 = (lin & 1) << 7;
    const int n0 = (lin >> 1) << 7;

    // fragment-major staging: thread t fetches data for (row_d, ch_d) so that
    // its linear GLD16 dest granule (=t) is exactly the read order.
    const int row_d = ((t >> 6) << 4) | (t & 15);   // 0..63 per half-tile
    const int ch_d  = (t >> 4) & 3;                 // 16B chunk within 64B

    const char* aA[2];
#pragma unroll
    for (int i = 0; i < 2; ++i)
        aA[i] = (const char*)Wq + (size_t)(m0 + i * 64 + row_d) * (KT * 2) + ch_d * 16;

    int bb[2], oh[2], ow[2];
    const char* bC[2] = {nullptr, nullptr};
#pragma unroll
    for (int i = 0; i < 2; ++i) {
        int n = n0 + i * 64 + row_d;
        bb[i] = n / 784;
        int r = n - bb[i] * 784;
        oh[i] = r / 28;
        ow[i] = r - oh[i] * 28;
        if constexpr (MODE == 2)
            bC[i] = (const char*)Xf +
                ((((size_t)bb[i] * 56 + oh[i] * 2) * 2 + 0) * 28 + ow[i]) * 512 + ch_d * 16;
    }

    // conflict-free fragment read offsets (bytes within an 8KB buffer)
    int aoffr[4], boffr[4];
#pragma unroll
    for (int x = 0; x < 4; ++x) {
        aoffr[x] = wm * 4096 + (x * 64 + fq * 16 + fr) * 16;
        boffr[x] = wn * 4096 + (x * 64 + fq * 16 + fr) * 16;
    }

    auto stage = [&](int ks, int buf) {
        const int kc = ks & 7;
#pragma unroll
        for (int i = 0; i < 2; ++i)
            GLD16(aA[i] + (size_t)ks * 64,
                  (char*)As + buf * 8192 + i * 4096 + wave * 1024);
        const int p = ks >> 3;
        const int kh = p / 3, kw = p - kh * 3;
#pragma unroll
        for (int i = 0; i < 2; ++i) {
            const char* bp;
            if constexpr (MODE == 2) {
                bp = bC[i] + ks * 64;
            } else if constexpr (MODE == 0) {
                int ih = oh[i] * 2 - 1 + kh;
                int par = (kw == 1) ? 0 : 1;
                int j = (kw == 0) ? ow[i] - 1 : ow[i];
                bool ok = ((unsigned)ih < 56u) && ((unsigned)j < 28u);
                bp = ok ? (const char*)Xf +
                          (((((size_t)bb[i] * 56 + ih) * 2 + par) * 28 + j) << 9) + kc * 64 + ch_d * 16
                        : (const char*)zp + ch_d * 16;
            } else {
                int ih = oh[i] - 1 + kh;
                int iw = ow[i] - 1 + kw;
                bool ok = ((unsigned)ih < 28u) && ((unsigned)iw < 28u);
                bp = ok ? (const char*)Xf +
                          ((((size_t)bb[i] * 28 + ih) * 28 + iw) << 9) + kc * 64 + ch_d * 16
                        : (const char*)zp + ch_d * 16;
            }
            GLD16(bp, (char*)Bs + buf * 8192 + i * 4096 + wave * 1024);
        }
    };

    f4 acc[4][4];
#pragma unroll
    for (int i = 0; i < 4; ++i)
#pragma unroll
        for (int j = 0; j < 4; ++j) acc[i][j] = f4{0.f, 0.f, 0.f, 0.f};

    stage(0, 0);
#pragma unroll 1
    for (int ks = 0; ks < NSTEP; ++ks) {
        const int cur = ks & 1;
        if (ks + 1 < NSTEP) {
            stage(ks + 1, cur ^ 1);
            asm volatile("s_waitcnt vmcnt(4)" ::: "memory");
        } else {
            asm volatile("s_waitcnt vmcnt(0)" ::: "memory");
        }
        __builtin_amdgcn_s_barrier();
        asm volatile("" ::: "memory");
        h8 af[4], bf[4];
#pragma unroll
        for (int x = 0; x < 4; ++x) {
            af[x] = *(const h8*)((const char*)As + cur * 8192 + aoffr[x]);
            bf[x] = *(const h8*)((const char*)Bs + cur * 8192 + boffr[x]);
        }
#pragma unroll
        for (int mi = 0; mi < 4; ++mi)
#pragma unroll
            for (int ni = 0; ni < 4; ++ni)
                acc[mi][ni] = __builtin_amdgcn_mfma_f32_16x16x32_f16(af[mi], bf[ni], acc[mi][ni], 0, 0, 0);
        asm volatile("" ::: "memory");
        __builtin_amdgcn_s_barrier();
    }

    if constexpr (MODE == 2) {
#pragma unroll
        for (int mi = 0; mi < 4; ++mi) {
            const int m = m0 + wm * 64 + mi * 16 + fq * 4;
            const f4 sc = *(const f4*)&scale[m];
#pragma unroll
            for (int ni = 0; ni < 4; ++ni) {
                const int n = n0 + wn * 64 + ni * 16 + fr;
                f4 s = acc[mi][ni] * sc;
                *(f4*)&Y[(size_t)n * 256 + m] = s;
            }
        }
    } else {
        float tmax = 0.f;
#pragma unroll
        for (int mi = 0; mi < 4; ++mi) {
            const int m = m0 + wm * 64 + mi * 16 + fq * 4;
            const f4 sc = *(const f4*)&scale[m];
            const f4 bi = *(const f4*)&bias[m];
#pragma unroll
            for (int ni = 0; ni < 4; ++ni) {
                const int n = n0 + wn * 64 + ni * 16 + fr;
                f4 v = acc[mi][ni] * sc + bi;
                f4 r;
                r.x = fmaxf(v.x, 0.f); r.y = fmaxf(v.y, 0.f);
                r.z = fmaxf(v.z, 0.f); r.w = fmaxf(v.w, 0.f);
                tmax = fmaxf(tmax, fmaxf(fmaxf(r.x, r.y), fmaxf(r.z, r.w)));
                *(f4*)&Y[(size_t)n * 256 + m] = r;
            }
        }
#pragma unroll
        for (int off = 32; off > 0; off >>= 1)
            tmax = fmaxf(tmax, __shfl_xor(tmax, off));
        if (lane == 0) wred[wave] = tmax;
        __syncthreads();
        if (t == 0) {
            float mx = fmaxf(fmaxf(wred[0], wred[1]), fmaxf(wred[2], wred[3]));
            atomicMax(&slots[(lin & (NSLOT - 1)) * SLOTSTRIDE], __float_as_int(mx));
        }
    }
}

// ---------------------------------------------------------------------------
__global__ void mid_k(const int* __restrict__ slotsA, const float* __restrict__ ws2,
                      const float* __restrict__ b2f, float* __restrict__ scale2,
                      float* __restrict__ bias2, float* __restrict__ a1p)
{
    const int o = threadIdx.x;
    const float a1 = fmaxf(slot_max(slotsA) / 1023.f, 1e-8f);
    const float s2 = ws2[o] * a1;
    float bq = fminf(fmaxf(rintf(b2f[o] / s2), -128.f), 127.f);
    scale2[o] = s2;
    bias2[o] = bq * s2;
    if (o == 0) a1p[0] = a1;
}

__global__ void quant_x2(const float* __restrict__ t1, const float* __restrict__ a1p,
                         _Float16* __restrict__ x2)
{
    const size_t i = (size_t)blockIdx.x * 256 + threadIdx.x;
    const float a1 = a1p[0];
    f4 v = ((const f4*)t1)[i];
    h4 o;
    o[0] = (_Float16)fminf(rintf(v.x / a1), 1023.f);
    o[1] = (_Float16)fminf(rintf(v.y / a1), 1023.f);
    o[2] = (_Float16)fminf(rintf(v.z / a1), 1023.f);
    o[3] = (_Float16)fminf(rintf(v.w / a1), 1023.f);
    ((h4*)x2)[i] = o;
}

__global__ void add_short_k(const float* __restrict__ t2, const float* __restrict__ sh,
                            const int* __restrict__ slotsB, int* __restrict__ slotsC,
                            float* __restrict__ o3)
{
    const float a2 = fmaxf(slot_max(slotsB) / 1023.f, 1e-8f);
    const float inv_a2 = 1.f / a2;
    float tmax = 0.f;
    const size_t base = (size_t)blockIdx.x * 256 + threadIdx.x;
#pragma unroll
    for (int it = 0; it < 4; ++it) {
        const size_t i = base + (size_t)it * 802816;   // 3136*256
        f4 v = ((const f4*)t2)[i];
        f4 s = ((const f4*)sh)[i];
        f4 r;
        r.x = fmaxf(fminf(rintf(v.x * inv_a2), 1023.f) * a2 + s.x, 0.f);
        r.y = fmaxf(fminf(rintf(v.y * inv_a2), 1023.f) * a2 + s.y, 0.f);
        r.z = fmaxf(fminf(rintf(v.z * inv_a2), 1023.f) * a2 + s.z, 0.f);
        r.w = fmaxf(fminf(rintf(v.w * inv_a2), 1023.f) * a2 + s.w, 0.f);
        ((f4*)o3)[i] = r;
        tmax = fmaxf(tmax, fmaxf(fmaxf(r.x, r.y), fmaxf(r.z, r.w)));
    }
#pragma unroll
    for (int off = 32; off > 0; off >>= 1)
        tmax = fmaxf(tmax, __shfl_xor(tmax, off));
    __shared__ float wred[4];
    if ((threadIdx.x & 63) == 0) wred[threadIdx.x >> 6] = tmax;
    __syncthreads();
    if (threadIdx.x == 0) {
        float mx = fmaxf(fmaxf(wred[0], wred[1]), fmaxf(wred[2], wred[3]));
        atomicMax(&slotsC[(blockIdx.x & (NSLOT - 1)) * SLOTSTRIDE], __float_as_int(mx));
    }
}

__global__ void finalize_k(const float* __restrict__ o3, const int* __restrict__ slotsC,
                           float* __restrict__ dout, int out_size)
{
    const int b = blockIdx.x / 28, oh = blockIdx.x - (blockIdx.x / 28) * 28;
    const float a3 = fmaxf(slot_max(slotsC) / 1023.f, 1e-8f);
    __shared__ float tile[28 * 257];
    const float* src = o3 + (size_t)(b * 28 + oh) * 28 * 256;
    for (int i = threadIdx.x; i < 7168; i += 256)
        tile[(i >> 8) * 257 + (i & 255)] = src[i];
    __syncthreads();
    for (int j = threadIdx.x; j < 7168; j += 256) {
        int c = j / 28, ww = j - (j / 28) * 28;
        float v = tile[ww * 257 + c];
        float q = fminf(rintf(v / a3), 1023.f);
        dout[(((size_t)b * 256 + c) * 28 + oh) * 28 + ww] = q * a3;
    }
    if (blockIdx.x == 0 && threadIdx.x == 0) dout[(size_t)out_size - 1] = a3;
}

// ---------------------------------------------------------------------------
extern "C" void kernel_launch(void* const* d_in, const int* in_sizes, int n_in,
                              void* d_out, int out_size, void* d_ws, size_t ws_size,
                              hipStream_t stream)
{
    const float* x   = (const float*)d_in[0];
    const float* as_ = (const float*)d_in[1];
    const float* wsc = (const float*)d_in[2];
    const float* w1  = (const float*)d_in[3];
    const float* g1  = (const float*)d_in[4];
    const float* b1  = (const float*)d_in[5];
    const float* m1  = (const float*)d_in[6];
    const float* v1  = (const float*)d_in[7];
    const float* w2  = (const float*)d_in[8];
    const float* g2  = (const float*)d_in[9];
    const float* b2  = (const float*)d_in[10];
    const float* m2  = (const float*)d_in[11];
    const float* v2  = (const float*)d_in[12];
    float* out = (float*)d_out;

    char* w = (char*)d_ws;
    size_t off = 0;
    auto alloc = [&](size_t bytes) { size_t c = off; off += (bytes + 255) & ~(size_t)255; return c; };
    const size_t oXF = alloc((size_t)64 * 56 * 56 * 256 * 2);  // parity NHWC fp16 hi/lo
    const size_t oY1 = alloc((size_t)NEL * 4);                 // t1 / o3
    const size_t oSH = alloc((size_t)NEL * 4);                 // shortcut
    const size_t oX2 = alloc((size_t)NEL * 2);                 // x2 fp16
    const size_t oW1 = alloc((size_t)256 * 2304 * 2);
    const size_t oW2 = alloc((size_t)256 * 2304 * 2);
    const size_t oWS = alloc((size_t)256 * 256 * 2);
    const size_t oSC = alloc((size_t)8 * 256 * 4);
    const size_t oMS = alloc(3 * NSLOT * SLOTSTRIDE * 4 + 2048);
    if (off > ws_size) {
        fprintf(stderr, "kernel_launch: ws too small: need %zu have %zu\n", off, ws_size);
        return;
    }

    _Float16* xf   = (_Float16*)(w + oXF);
    float*    y1   = (float*)(w + oY1);
    float*    sh   = (float*)(w + oSH);
    _Float16* x2   = (_Float16*)(w + oX2);
    _Float16* wq1  = (_Float16*)(w + oW1);
    _Float16* wq2  = (_Float16*)(w + oW2);
    _Float16* wscd = (_Float16*)(w + oWS);
    float* scl = (float*)(w + oSC);
    float *scale1 = scl, *bias1 = scl + 256, *scale_sc = scl + 512, *ws2 = scl + 768,
          *b2f = scl + 1024, *scale2 = scl + 1280, *bias2 = scl + 1536, *a1p = scl + 1792;
    int* slots  = (int*)(w + oMS);
    int* slotsA = slots;
    int* slotsB = slots + NSLOT * SLOTSTRIDE;
    int* slotsC = slots + 2 * NSLOT * SLOTSTRIDE;
    _Float16* zp = (_Float16*)(w + oMS + 3 * NSLOT * SLOTSTRIDE * 4);
    float* y2 = (float*)(w + oXF);   // reuse xf region (dead after conv1)
    float* o3 = (float*)(w + oY1);   // reuse t1 region (dead after quant_x2)

    init_ws<<<1, 256, 0, stream>>>(slots, zp);
    prep_wsc<<<256, 256, 0, stream>>>(wsc, as_, wscd, scale_sc);
    prep_w1<<<256, 256, 0, stream>>>(w1, g1, b1, m1, v1, as_, wq1, scale1, bias1);
    prep_w2<<<256, 256, 0, stream>>>(w2, g2, b2, m2, v2, wq2, ws2, b2f);
    prep_x<<<64 * 56, 256, 0, stream>>>(x, as_, xf);
    conv_k<2><<<784, 256, 0, stream>>>(xf, wscd, scale_sc, nullptr, sh, nullptr, zp);
    conv_k<0><<<784, 256, 0, stream>>>(xf, wq1, scale1, bias1, y1, slotsA, zp);
    mid_k<<<1, 256, 0, stream>>>(slotsA, ws2, b2f, scale2, bias2, a1p);
    quant_x2<<<12544, 256, 0, stream>>>(y1, a1p, x2);
    conv_k<1><<<784, 256, 0, stream>>>(x2, wq2, scale2, bias2, y2, slotsB, zp);
    add_short_k<<<3136, 256, 0, stream>>>(y2, sh, slotsB, slotsC, o3);
    finalize_k<<<64 * 28, 256, 0, stream>>>(o3, slotsC, out, out_size);
}

// Round 4
// 454.530 us; speedup vs baseline: 1.0014x; 1.0014x over previous
//
#include <hip/hip_runtime.h>
#include <cstdio>
#include <cstdint>

typedef _Float16 h8 __attribute__((ext_vector_type(8)));
typedef _Float16 h4 __attribute__((ext_vector_type(4)));
typedef _Float16 h2 __attribute__((ext_vector_type(2)));
typedef float f4 __attribute__((ext_vector_type(4)));

#define GLD16(g, l) __builtin_amdgcn_global_load_lds( \
    (const __attribute__((address_space(1))) void*)(g), \
    (__attribute__((address_space(3))) void*)(l), 16, 0, 0)

static constexpr int HOUT = 28;
static constexpr long long NSP = 64LL * HOUT * HOUT;     // 50176 output pixels
static constexpr long long NEL = NSP * 256;              // 12,845,056 output elems
static constexpr int NSLOT = 64;                         // spread atomic slots
static constexpr int SLOTSTRIDE = 32;                    // 128B apart

// ---------------------------------------------------------------------------
__global__ void init_ws(int* __restrict__ slots, _Float16* __restrict__ zp)
{
    const int t = threadIdx.x;
    for (int i = t; i < 3 * NSLOT * SLOTSTRIDE; i += 256) slots[i] = 0;
    for (int i = t; i < 512; i += 256) zp[i] = (_Float16)0.f;
}

__device__ __forceinline__ float slot_max(const int* __restrict__ slots)
{
    float m = 0.f;
#pragma unroll
    for (int i = 0; i < NSLOT; ++i) m = fmaxf(m, __int_as_float(slots[i * SLOTSTRIDE]));
    return m;
}

// ---------------------------------------------------------------------------
// weight prep: per-output-channel symmetric 8-bit quant, BN fold, k-reorder.
// conv1 weights channel-DUPLICATED (k = p*256 + cc, cc=ci or ci+128) to match
// the hi/lo split input.
__global__ void prep_w1(const float* __restrict__ w1, const float* __restrict__ g1,
                        const float* __restrict__ b1, const float* __restrict__ m1,
                        const float* __restrict__ v1, const float* __restrict__ asp,
                        _Float16* __restrict__ wq, float* __restrict__ scale1,
                        float* __restrict__ bias1)
{
    const int o = blockIdx.x, t = threadIdx.x;
    const float f = g1[o] * rsqrtf(v1[o] + 1e-5f);
    const float* wr = w1 + (size_t)o * 1152;
    float amax = 0.f;
    for (int i = t; i < 1152; i += 256) amax = fmaxf(amax, fabsf(wr[i] * f));
    __shared__ float red[256];
    red[t] = amax; __syncthreads();
    for (int s = 128; s > 0; s >>= 1) { if (t < s) red[t] = fmaxf(red[t], red[t + s]); __syncthreads(); }
    const float ws = fmaxf(red[0] / 127.f, 1e-8f);
    for (int idx = t; idx < 2304; idx += 256) {
        int p = idx >> 8, cc = idx & 255, ci = cc & 127;
        float q = fminf(fmaxf(rintf(wr[ci * 9 + p] * f / ws), -128.f), 127.f);
        wq[(size_t)o * 2304 + idx] = (_Float16)q;
    }
    if (t == 0) {
        const float bs = ws * asp[0];
        const float bf = b1[o] - m1[o] * f;
        float bq = fminf(fmaxf(rintf(bf / bs), -128.f), 127.f);
        scale1[o] = bs;
        bias1[o] = bq * bs;
    }
}

__global__ void prep_w2(const float* __restrict__ w2, const float* __restrict__ g2,
                        const float* __restrict__ b2, const float* __restrict__ m2,
                        const float* __restrict__ v2,
                        _Float16* __restrict__ wq, float* __restrict__ ws2,
                        float* __restrict__ b2f)
{
    const int o = blockIdx.x, t = threadIdx.x;
    const float f = g2[o] * rsqrtf(v2[o] + 1e-5f);
    const float* wr = w2 + (size_t)o * 2304;
    float amax = 0.f;
    for (int i = t; i < 2304; i += 256) amax = fmaxf(amax, fabsf(wr[i] * f));
    __shared__ float red[256];
    red[t] = amax; __syncthreads();
    for (int s = 128; s > 0; s >>= 1) { if (t < s) red[t] = fmaxf(red[t], red[t + s]); __syncthreads(); }
    const float ws = fmaxf(red[0] / 127.f, 1e-8f);
    for (int idx = t; idx < 2304; idx += 256) {
        int p = idx >> 8, ci = idx & 255;
        float q = fminf(fmaxf(rintf(wr[ci * 9 + p] * f / ws), -128.f), 127.f);
        wq[(size_t)o * 2304 + idx] = (_Float16)q;
    }
    if (t == 0) { ws2[o] = ws; b2f[o] = b2[o] - m2[o] * f; }
}

__global__ void prep_wsc(const float* __restrict__ wsc, const float* __restrict__ asp,
                         _Float16* __restrict__ wq, float* __restrict__ scale_sc)
{
    const int o = blockIdx.x, t = threadIdx.x;
    const float* wr = wsc + (size_t)o * 128;
    float amax = (t < 128) ? fabsf(wr[t]) : 0.f;
    __shared__ float red[256];
    red[t] = amax; __syncthreads();
    for (int s = 128; s > 0; s >>= 1) { if (t < s) red[t] = fmaxf(red[t], red[t + s]); __syncthreads(); }
    const float ws = fmaxf(red[0] / 127.f, 1e-8f);
    float q = fminf(fmaxf(rintf(wr[t & 127] / ws), -128.f), 127.f);
    wq[(size_t)o * 256 + t] = (_Float16)q;   // duplicated layout [o][256]
    if (t == 0) scale_sc[o] = ws * asp[0];
}

// ---------------------------------------------------------------------------
// x (NCHW f32) -> column-parity NHWC fp16 hi/lo pairs of x/act_scale.
// layout: xf[b][ih][par][j][256] where iw = 2*j + par. one block per (b,h).
__global__ void prep_x(const float* __restrict__ x, const float* __restrict__ asp,
                       _Float16* __restrict__ xf)
{
    const int b = blockIdx.x / 56, h = blockIdx.x - (blockIdx.x / 56) * 56;
    const float as = asp[0];
    __shared__ float tile[56 * 129];
    const float* src = x + ((size_t)b * 128 * 56 + h) * 56;   // x[b][c][h][w]
    for (int i = threadIdx.x; i < 7168; i += 256) {
        int c = i / 56, ww = i - c * 56;
        tile[ww * 129 + c] = src[(size_t)c * 3136 + ww] / as;
    }
    __syncthreads();
    _Float16* dst = xf + (size_t)(b * 56 + h) * 2 * 28 * 256;
    for (int j = threadIdx.x; j < 7168; j += 256) {
        int ww = j >> 7, q = j & 127;
        int cc = q * 2;
        int c0 = cc & 127, c1 = (cc + 1) & 127;
        float x0 = tile[ww * 129 + c0];
        float x1 = tile[ww * 129 + c1];
        h2 o;
        if (cc < 128) { o[0] = (_Float16)x0; o[1] = (_Float16)x1; }
        else {
            _Float16 h0 = (_Float16)x0, h1 = (_Float16)x1;
            o[0] = (_Float16)(x0 - (float)h0);
            o[1] = (_Float16)(x1 - (float)h1);
        }
        size_t eo = ((size_t)(ww & 1) * 28 + (ww >> 1)) * 256 + (size_t)cc;
        *(h2*)&dst[eo] = o;
    }
}

// ---------------------------------------------------------------------------
// pipelined implicit-GEMM conv: BM=BN=128, BK=32, 4 waves, f16 MFMA.
// 3-buffer LDS ring, prefetch depth 2, counted vmcnt(8) -- stage(ks+3) issued
// before compute(ks) so ~2.5 K-steps of compute cover the load latency.
// Fragment-major LDS (conflict-free b128 reads) via permuted global source.
// MODE 0: conv1 3x3 s2 on parity xf, with fused 1x1-s2 shortcut at p==4.
// MODE 1: conv2 3x3 s1.
template<int MODE>
__global__ __launch_bounds__(256, 2)
void conv_k(const _Float16* __restrict__ Xf,
            const _Float16* __restrict__ Wq,     // [256][2304]
            const _Float16* __restrict__ Wsc,    // [256][256] dup (MODE 0)
            const float* __restrict__ scale,
            const float* __restrict__ bias,
            const float* __restrict__ scale_sc,
            float* __restrict__ Y,               // [N][256]
            float* __restrict__ Ysc,             // [N][256] shortcut (MODE 0)
            int* __restrict__ slots,
            const _Float16* __restrict__ zp)
{
    constexpr int KT = 2304;
    constexpr int NSTEP = KT / 32;               // 72
    __shared__ __attribute__((aligned(16))) _Float16 As[3][4096];  // 3 x 8KB
    __shared__ __attribute__((aligned(16))) _Float16 Bs[3][4096];
    __shared__ float wred[4];

    const int t = threadIdx.x;
    const int wave = t >> 6, lane = t & 63;
    const int wm = wave >> 1, wn = wave & 1;
    const int fr = lane & 15, fq = lane >> 4;

    // bijective XCD-chunked swizzle over 784 blocks (8 XCDs x 98)
    const int id = blockIdx.x;
    const int lin = (id & 7) * 98 + (id >> 3);
    const int m0 = (lin & 1) << 7;
    const int n0 = (lin >> 1) << 7;

    // fragment-major staging coords
    const int row_d = ((t >> 6) << 4) | (t & 15);   // 0..63 per half-tile
    const int ch_d  = (t >> 4) & 3;                 // 16B chunk within 64B

    const char* aA[2];
#pragma unroll
    for (int i = 0; i < 2; ++i)
        aA[i] = (const char*)Wq + (size_t)(m0 + i * 64 + row_d) * (KT * 2) + ch_d * 16;

    int bb[2], oh[2], ow[2];
#pragma unroll
    for (int i = 0; i < 2; ++i) {
        int n = n0 + i * 64 + row_d;
        bb[i] = n / 784;
        int r = n - bb[i] * 784;
        oh[i] = r / 28;
        ow[i] = r - oh[i] * 28;
    }

    int aoffr[4], boffr[4];
#pragma unroll
    for (int x = 0; x < 4; ++x) {
        aoffr[x] = wm * 4096 + (x * 64 + fq * 16 + fr) * 16;
        boffr[x] = wn * 4096 + (x * 64 + fq * 16 + fr) * 16;
    }

    const char* bcur[2] = {nullptr, nullptr};
    auto stage = [&](int ks, int buf) {
        if (ks >= NSTEP) return;
        const int kc = ks & 7;
#pragma unroll
        for (int i = 0; i < 2; ++i)
            GLD16(aA[i] + (size_t)ks * 64, (char*)As + buf * 8192 + i * 4096 + wave * 1024);
        if (kc == 0) {   // new tap: compute base pointers once per 8 stages
            const int p = ks >> 3;
            const int kh = p / 3, kw = p - kh * 3;
#pragma unroll
            for (int i = 0; i < 2; ++i) {
                if constexpr (MODE == 0) {
                    int ih = oh[i] * 2 - 1 + kh;
                    int par = (kw == 1) ? 0 : 1;
                    int j = (kw == 0) ? ow[i] - 1 : ow[i];
                    bool ok = ((unsigned)ih < 56u) && ((unsigned)j < 28u);
                    bcur[i] = ok ? (const char*)Xf +
                                   (((((size_t)bb[i] * 56 + ih) * 2 + par) * 28 + j) << 9) + ch_d * 16
                                 : (const char*)zp + ch_d * 16;
                } else {
                    int ih = oh[i] - 1 + kh;
                    int iw = ow[i] - 1 + kw;
                    bool ok = ((unsigned)ih < 28u) && ((unsigned)iw < 28u);
                    bcur[i] = ok ? (const char*)Xf +
                                   ((((size_t)bb[i] * 28 + ih) * 28 + iw) << 9) + ch_d * 16
                                 : (const char*)zp + ch_d * 16;
                }
            }
        }
#pragma unroll
        for (int i = 0; i < 2; ++i)
            GLD16(bcur[i] + (size_t)kc * 64, (char*)Bs + buf * 8192 + i * 4096 + wave * 1024);
    };

    f4 acc[4][4];
    f4 accs[4][4];
#pragma unroll
    for (int i = 0; i < 4; ++i)
#pragma unroll
        for (int j = 0; j < 4; ++j) {
            acc[i][j] = f4{0.f, 0.f, 0.f, 0.f};
            if constexpr (MODE == 0) accs[i][j] = f4{0.f, 0.f, 0.f, 0.f};
        }

    stage(0, 0); stage(1, 1); stage(2, 2);
    int bufc = 0;
#pragma unroll 1
    for (int ks = 0; ks < NSTEP; ++ks) {
        if (ks + 2 < NSTEP)       asm volatile("s_waitcnt vmcnt(8)" ::: "memory");
        else if (ks + 2 == NSTEP) asm volatile("s_waitcnt vmcnt(4)" ::: "memory");
        else                      asm volatile("s_waitcnt vmcnt(0)" ::: "memory");
        __builtin_amdgcn_s_barrier();

        h8 af[4], bf[4];
#pragma unroll
        for (int x = 0; x < 4; ++x) {
            af[x] = *(const h8*)((const char*)As + bufc * 8192 + aoffr[x]);
            bf[x] = *(const h8*)((const char*)Bs + bufc * 8192 + boffr[x]);
        }
        asm volatile("s_waitcnt lgkmcnt(0)" ::: "memory");
        __builtin_amdgcn_s_barrier();

        // shortcut fragments issued BEFORE stage loads so their wait is
        // vmcnt(4), not a pipeline drain
        h8 sf[4];
        if constexpr (MODE == 0) {
            if ((ks >> 3) == 4) {
#pragma unroll
                for (int mi = 0; mi < 4; ++mi)
                    sf[mi] = *(const h8*)&Wsc[(size_t)(m0 + wm * 64 + mi * 16 + fr) * 256 +
                                              (ks & 7) * 32 + fq * 8];
            }
        }
        stage(ks + 3, bufc);

#pragma unroll
        for (int mi = 0; mi < 4; ++mi)
#pragma unroll
            for (int ni = 0; ni < 4; ++ni)
                acc[mi][ni] = __builtin_amdgcn_mfma_f32_16x16x32_f16(af[mi], bf[ni], acc[mi][ni], 0, 0, 0);
        if constexpr (MODE == 0) {
            if ((ks >> 3) == 4) {
#pragma unroll
                for (int mi = 0; mi < 4; ++mi)
#pragma unroll
                    for (int ni = 0; ni < 4; ++ni)
                        accs[mi][ni] = __builtin_amdgcn_mfma_f32_16x16x32_f16(sf[mi], bf[ni], accs[mi][ni], 0, 0, 0);
            }
        }
        bufc = (bufc == 2) ? 0 : bufc + 1;
    }

    float tmax = 0.f;
#pragma unroll
    for (int mi = 0; mi < 4; ++mi) {
        const int m = m0 + wm * 64 + mi * 16 + fq * 4;
        const f4 sc = *(const f4*)&scale[m];
        const f4 bi = *(const f4*)&bias[m];
        f4 ssc;
        if constexpr (MODE == 0) ssc = *(const f4*)&scale_sc[m];
#pragma unroll
        for (int ni = 0; ni < 4; ++ni) {
            const int n = n0 + wn * 64 + ni * 16 + fr;
            f4 v = acc[mi][ni] * sc + bi;
            f4 r;
            r.x = fmaxf(v.x, 0.f); r.y = fmaxf(v.y, 0.f);
            r.z = fmaxf(v.z, 0.f); r.w = fmaxf(v.w, 0.f);
            tmax = fmaxf(tmax, fmaxf(fmaxf(r.x, r.y), fmaxf(r.z, r.w)));
            *(f4*)&Y[(size_t)n * 256 + m] = r;
            if constexpr (MODE == 0) {
                f4 s = accs[mi][ni] * ssc;
                *(f4*)&Ysc[(size_t)n * 256 + m] = s;
            }
        }
    }
#pragma unroll
    for (int off = 32; off > 0; off >>= 1)
        tmax = fmaxf(tmax, __shfl_xor(tmax, off));
    if (lane == 0) wred[wave] = tmax;
    __syncthreads();
    if (t == 0) {
        float mx = fmaxf(fmaxf(wred[0], wred[1]), fmaxf(wred[2], wred[3]));
        atomicMax(&slots[(lin & (NSLOT - 1)) * SLOTSTRIDE], __float_as_int(mx));
    }
}

// ---------------------------------------------------------------------------
__global__ void mid_k(const int* __restrict__ slotsA, const float* __restrict__ ws2,
                      const float* __restrict__ b2f, float* __restrict__ scale2,
                      float* __restrict__ bias2, float* __restrict__ a1p)
{
    const int o = threadIdx.x;
    const float a1 = fmaxf(slot_max(slotsA) / 1023.f, 1e-8f);
    const float s2 = ws2[o] * a1;
    float bq = fminf(fmaxf(rintf(b2f[o] / s2), -128.f), 127.f);
    scale2[o] = s2;
    bias2[o] = bq * s2;
    if (o == 0) a1p[0] = a1;
}

__global__ void quant_x2(const float* __restrict__ t1, const float* __restrict__ a1p,
                         _Float16* __restrict__ x2)
{
    const size_t i = (size_t)blockIdx.x * 256 + threadIdx.x;
    const float a1 = a1p[0];
    f4 v = ((const f4*)t1)[i];
    h4 o;
    o[0] = (_Float16)fminf(rintf(v.x / a1), 1023.f);
    o[1] = (_Float16)fminf(rintf(v.y / a1), 1023.f);
    o[2] = (_Float16)fminf(rintf(v.z / a1), 1023.f);
    o[3] = (_Float16)fminf(rintf(v.w / a1), 1023.f);
    ((h4*)x2)[i] = o;
}

__global__ void add_short_k(const float* __restrict__ t2, const float* __restrict__ sh,
                            const int* __restrict__ slotsB, int* __restrict__ slotsC,
                            float* __restrict__ o3)
{
    const float a2 = fmaxf(slot_max(slotsB) / 1023.f, 1e-8f);
    const float inv_a2 = 1.f / a2;
    float tmax = 0.f;
    const size_t base = (size_t)blockIdx.x * 256 + threadIdx.x;
#pragma unroll
    for (int it = 0; it < 4; ++it) {
        const size_t i = base + (size_t)it * 802816;   // 3136*256
        f4 v = ((const f4*)t2)[i];
        f4 s = ((const f4*)sh)[i];
        f4 r;
        r.x = fmaxf(fminf(rintf(v.x * inv_a2), 1023.f) * a2 + s.x, 0.f);
        r.y = fmaxf(fminf(rintf(v.y * inv_a2), 1023.f) * a2 + s.y, 0.f);
        r.z = fmaxf(fminf(rintf(v.z * inv_a2), 1023.f) * a2 + s.z, 0.f);
        r.w = fmaxf(fminf(rintf(v.w * inv_a2), 1023.f) * a2 + s.w, 0.f);
        ((f4*)o3)[i] = r;
        tmax = fmaxf(tmax, fmaxf(fmaxf(r.x, r.y), fmaxf(r.z, r.w)));
    }
#pragma unroll
    for (int off = 32; off > 0; off >>= 1)
        tmax = fmaxf(tmax, __shfl_xor(tmax, off));
    __shared__ float wred[4];
    if ((threadIdx.x & 63) == 0) wred[threadIdx.x >> 6] = tmax;
    __syncthreads();
    if (threadIdx.x == 0) {
        float mx = fmaxf(fmaxf(wred[0], wred[1]), fmaxf(wred[2], wred[3]));
        atomicMax(&slotsC[(blockIdx.x & (NSLOT - 1)) * SLOTSTRIDE], __float_as_int(mx));
    }
}

__global__ void finalize_k(const float* __restrict__ o3, const int* __restrict__ slotsC,
                           float* __restrict__ dout, int out_size)
{
    const int b = blockIdx.x / 28, oh = blockIdx.x - (blockIdx.x / 28) * 28;
    const float a3 = fmaxf(slot_max(slotsC) / 1023.f, 1e-8f);
    __shared__ float tile[28 * 257];
    const float* src = o3 + (size_t)(b * 28 + oh) * 28 * 256;
    for (int i = threadIdx.x; i < 7168; i += 256)
        tile[(i >> 8) * 257 + (i & 255)] = src[i];
    __syncthreads();
    for (int j = threadIdx.x; j < 7168; j += 256) {
        int c = j / 28, ww = j - (j / 28) * 28;
        float v = tile[ww * 257 + c];
        float q = fminf(rintf(v / a3), 1023.f);
        dout[(((size_t)b * 256 + c) * 28 + oh) * 28 + ww] = q * a3;
    }
    if (blockIdx.x == 0 && threadIdx.x == 0) dout[(size_t)out_size - 1] = a3;
}

// ---------------------------------------------------------------------------
extern "C" void kernel_launch(void* const* d_in, const int* in_sizes, int n_in,
                              void* d_out, int out_size, void* d_ws, size_t ws_size,
                              hipStream_t stream)
{
    const float* x   = (const float*)d_in[0];
    const float* as_ = (const float*)d_in[1];
    const float* wsc = (const float*)d_in[2];
    const float* w1  = (const float*)d_in[3];
    const float* g1  = (const float*)d_in[4];
    const float* b1  = (const float*)d_in[5];
    const float* m1  = (const float*)d_in[6];
    const float* v1  = (const float*)d_in[7];
    const float* w2  = (const float*)d_in[8];
    const float* g2  = (const float*)d_in[9];
    const float* b2  = (const float*)d_in[10];
    const float* m2  = (const float*)d_in[11];
    const float* v2  = (const float*)d_in[12];
    float* out = (float*)d_out;

    char* w = (char*)d_ws;
    size_t off = 0;
    auto alloc = [&](size_t bytes) { size_t c = off; off += (bytes + 255) & ~(size_t)255; return c; };
    const size_t oXF = alloc((size_t)64 * 56 * 56 * 256 * 2);  // parity NHWC fp16 hi/lo
    const size_t oY1 = alloc((size_t)NEL * 4);                 // t1 / o3
    const size_t oSH = alloc((size_t)NEL * 4);                 // shortcut
    const size_t oX2 = alloc((size_t)NEL * 2);                 // x2 fp16
    const size_t oW1 = alloc((size_t)256 * 2304 * 2);
    const size_t oW2 = alloc((size_t)256 * 2304 * 2);
    const size_t oWS = alloc((size_t)256 * 256 * 2);
    const size_t oSC = alloc((size_t)8 * 256 * 4);
    const size_t oMS = alloc(3 * NSLOT * SLOTSTRIDE * 4 + 2048);
    if (off > ws_size) {
        fprintf(stderr, "kernel_launch: ws too small: need %zu have %zu\n", off, ws_size);
        return;
    }

    _Float16* xf   = (_Float16*)(w + oXF);
    float*    y1   = (float*)(w + oY1);
    float*    sh   = (float*)(w + oSH);
    _Float16* x2   = (_Float16*)(w + oX2);
    _Float16* wq1  = (_Float16*)(w + oW1);
    _Float16* wq2  = (_Float16*)(w + oW2);
    _Float16* wscd = (_Float16*)(w + oWS);
    float* scl = (float*)(w + oSC);
    float *scale1 = scl, *bias1 = scl + 256, *scale_sc = scl + 512, *ws2 = scl + 768,
          *b2f = scl + 1024, *scale2 = scl + 1280, *bias2 = scl + 1536, *a1p = scl + 1792;
    int* slots  = (int*)(w + oMS);
    int* slotsA = slots;
    int* slotsB = slots + NSLOT * SLOTSTRIDE;
    int* slotsC = slots + 2 * NSLOT * SLOTSTRIDE;
    _Float16* zp = (_Float16*)(w + oMS + 3 * NSLOT * SLOTSTRIDE * 4);
    float* y2 = (float*)(w + oXF);   // reuse xf region (dead after conv1)
    float* o3 = (float*)(w + oY1);   // reuse t1 region (dead after quant_x2)

    init_ws<<<1, 256, 0, stream>>>(slots, zp);
    prep_wsc<<<256, 256, 0, stream>>>(wsc, as_, wscd, scale_sc);
    prep_w1<<<256, 256, 0, stream>>>(w1, g1, b1, m1, v1, as_, wq1, scale1, bias1);
    prep_w2<<<256, 256, 0, stream>>>(w2, g2, b2, m2, v2, wq2, ws2, b2f);
    prep_x<<<64 * 56, 256, 0, stream>>>(x, as_, xf);
    conv_k<0><<<784, 256, 0, stream>>>(xf, wq1, wscd, scale1, bias1, scale_sc,
                                       y1, sh, slotsA, zp);
    mid_k<<<1, 256, 0, stream>>>(slotsA, ws2, b2f, scale2, bias2, a1p);
    quant_x2<<<12544, 256, 0, stream>>>(y1, a1p, x2);
    conv_k<1><<<784, 256, 0, stream>>>(x2, wq2, nullptr, scale2, bias2, nullptr,
                                       y2, nullptr, slotsB, zp);
    add_short_k<<<3136, 256, 0, stream>>>(y2, sh, slotsB, slotsC, o3);
    finalize_k<<<64 * 28, 256, 0, stream>>>(o3, slotsC, out, out_size);
}

// Round 5
// 366.448 us; speedup vs baseline: 1.2421x; 1.2404x over previous
//
#include <hip/hip_runtime.h>
#include <cstdio>
#include <cstdint>

typedef _Float16 h8 __attribute__((ext_vector_type(8)));
typedef _Float16 h4 __attribute__((ext_vector_type(4)));
typedef _Float16 h2 __attribute__((ext_vector_type(2)));
typedef float f4 __attribute__((ext_vector_type(4)));

#define GLD16(g, l) __builtin_amdgcn_global_load_lds( \
    (const __attribute__((address_space(1))) void*)(g), \
    (__attribute__((address_space(3))) void*)(l), 16, 0, 0)

static constexpr int HOUT = 28;
static constexpr long long NSP = 64LL * HOUT * HOUT;     // 50176 output pixels
static constexpr long long NEL = NSP * 256;              // 12,845,056 output elems
static constexpr int NSLOT = 64;                         // spread atomic slots
static constexpr int SLOTSTRIDE = 32;                    // 128B apart

// ---------------------------------------------------------------------------
__global__ void init_ws(int* __restrict__ slots, _Float16* __restrict__ zp)
{
    const int t = threadIdx.x;
    for (int i = t; i < 3 * NSLOT * SLOTSTRIDE; i += 256) slots[i] = 0;
    for (int i = t; i < 512; i += 256) zp[i] = (_Float16)0.f;
}

__device__ __forceinline__ float slot_max(const int* __restrict__ slots)
{
    float m = 0.f;
#pragma unroll
    for (int i = 0; i < NSLOT; ++i) m = fmaxf(m, __int_as_float(slots[i * SLOTSTRIDE]));
    return m;
}

// ---------------------------------------------------------------------------
// weight prep: per-output-channel symmetric 8-bit quant, BN fold, k-reorder.
// conv1 weights channel-DUPLICATED (k = p*256 + cc, cc=ci or ci+128) to match
// the hi/lo split input.
__global__ void prep_w1(const float* __restrict__ w1, const float* __restrict__ g1,
                        const float* __restrict__ b1, const float* __restrict__ m1,
                        const float* __restrict__ v1, const float* __restrict__ asp,
                        _Float16* __restrict__ wq, float* __restrict__ scale1,
                        float* __restrict__ bias1)
{
    const int o = blockIdx.x, t = threadIdx.x;
    const float f = g1[o] * rsqrtf(v1[o] + 1e-5f);
    const float* wr = w1 + (size_t)o * 1152;
    float amax = 0.f;
    for (int i = t; i < 1152; i += 256) amax = fmaxf(amax, fabsf(wr[i] * f));
    __shared__ float red[256];
    red[t] = amax; __syncthreads();
    for (int s = 128; s > 0; s >>= 1) { if (t < s) red[t] = fmaxf(red[t], red[t + s]); __syncthreads(); }
    const float ws = fmaxf(red[0] / 127.f, 1e-8f);
    for (int idx = t; idx < 2304; idx += 256) {
        int p = idx >> 8, cc = idx & 255, ci = cc & 127;
        float q = fminf(fmaxf(rintf(wr[ci * 9 + p] * f / ws), -128.f), 127.f);
        wq[(size_t)o * 2304 + idx] = (_Float16)q;
    }
    if (t == 0) {
        const float bs = ws * asp[0];
        const float bf = b1[o] - m1[o] * f;
        float bq = fminf(fmaxf(rintf(bf / bs), -128.f), 127.f);
        scale1[o] = bs;
        bias1[o] = bq * bs;
    }
}

__global__ void prep_w2(const float* __restrict__ w2, const float* __restrict__ g2,
                        const float* __restrict__ b2, const float* __restrict__ m2,
                        const float* __restrict__ v2,
                        _Float16* __restrict__ wq, float* __restrict__ ws2,
                        float* __restrict__ b2f)
{
    const int o = blockIdx.x, t = threadIdx.x;
    const float f = g2[o] * rsqrtf(v2[o] + 1e-5f);
    const float* wr = w2 + (size_t)o * 2304;
    float amax = 0.f;
    for (int i = t; i < 2304; i += 256) amax = fmaxf(amax, fabsf(wr[i] * f));
    __shared__ float red[256];
    red[t] = amax; __syncthreads();
    for (int s = 128; s > 0; s >>= 1) { if (t < s) red[t] = fmaxf(red[t], red[t + s]); __syncthreads(); }
    const float ws = fmaxf(red[0] / 127.f, 1e-8f);
    for (int idx = t; idx < 2304; idx += 256) {
        int p = idx >> 8, ci = idx & 255;
        float q = fminf(fmaxf(rintf(wr[ci * 9 + p] * f / ws), -128.f), 127.f);
        wq[(size_t)o * 2304 + idx] = (_Float16)q;
    }
    if (t == 0) { ws2[o] = ws; b2f[o] = b2[o] - m2[o] * f; }
}

__global__ void prep_wsc(const float* __restrict__ wsc, const float* __restrict__ asp,
                         _Float16* __restrict__ wq, float* __restrict__ scale_sc)
{
    const int o = blockIdx.x, t = threadIdx.x;
    const float* wr = wsc + (size_t)o * 128;
    float amax = (t < 128) ? fabsf(wr[t]) : 0.f;
    __shared__ float red[256];
    red[t] = amax; __syncthreads();
    for (int s = 128; s > 0; s >>= 1) { if (t < s) red[t] = fmaxf(red[t], red[t + s]); __syncthreads(); }
    const float ws = fmaxf(red[0] / 127.f, 1e-8f);
    float q = fminf(fmaxf(rintf(wr[t & 127] / ws), -128.f), 127.f);
    wq[(size_t)o * 256 + t] = (_Float16)q;   // duplicated layout [o][256]
    if (t == 0) scale_sc[o] = ws * asp[0];
}

// ---------------------------------------------------------------------------
// x (NCHW f32) -> column-parity NHWC fp16 hi/lo pairs of x/act_scale.
// layout: xf[b][ih][par][j][256] where iw = 2*j + par. one block per (b,h).
__global__ void prep_x(const float* __restrict__ x, const float* __restrict__ asp,
                       _Float16* __restrict__ xf)
{
    const int b = blockIdx.x / 56, h = blockIdx.x - (blockIdx.x / 56) * 56;
    const float as = asp[0];
    __shared__ float tile[56 * 129];
    const float* src = x + ((size_t)b * 128 * 56 + h) * 56;   // x[b][c][h][w]
    for (int i = threadIdx.x; i < 7168; i += 256) {
        int c = i / 56, ww = i - c * 56;
        tile[ww * 129 + c] = src[(size_t)c * 3136 + ww] / as;
    }
    __syncthreads();
    _Float16* dst = xf + (size_t)(b * 56 + h) * 2 * 28 * 256;
    for (int j = threadIdx.x; j < 7168; j += 256) {
        int ww = j >> 7, q = j & 127;
        int cc = q * 2;
        int c0 = cc & 127, c1 = (cc + 1) & 127;
        float x0 = tile[ww * 129 + c0];
        float x1 = tile[ww * 129 + c1];
        h2 o;
        if (cc < 128) { o[0] = (_Float16)x0; o[1] = (_Float16)x1; }
        else {
            _Float16 h0 = (_Float16)x0, h1 = (_Float16)x1;
            o[0] = (_Float16)(x0 - (float)h0);
            o[1] = (_Float16)(x1 - (float)h1);
        }
        size_t eo = ((size_t)(ww & 1) * 28 + (ww >> 1)) * 256 + (size_t)cc;
        *(h2*)&dst[eo] = o;
    }
}

// ---------------------------------------------------------------------------
// big-tile pipelined implicit-GEMM conv:
//   block = BM 256 (all of M) x BN 256 pixels, BK=32, 512 threads = 8 waves,
//   wave-tile 128x64 (2M x 4N wave grid) -> 384 B LDS per MFMA (m201 ratio).
//   3-slot LDS ring (96KB), stage lead 2 K-tiles, counted vmcnt(4) -- never 0
//   in the main loop. One barrier per K-step. Fragment-major LDS layout
//   (conflict-free ds_read_b128) via per-lane global source permutation.
// MODE 0: conv1 3x3 s2 on parity xf (+ shortcut recomputed after main loop
//         from global, register-direct, reusing acc). MODE 1: conv2 3x3 s1.
template<int MODE>
__global__ __launch_bounds__(512, 1)
void conv_k(const _Float16* __restrict__ Xf,
            const _Float16* __restrict__ Wq,     // [256][2304]
            const _Float16* __restrict__ Wsc,    // [256][256] dup (MODE 0)
            const float* __restrict__ scale,
            const float* __restrict__ bias,
            const float* __restrict__ scale_sc,
            float* __restrict__ Y,               // [N][256]
            float* __restrict__ Ysc,             // [N][256] shortcut (MODE 0)
            int* __restrict__ slots,
            const _Float16* __restrict__ zp)
{
    constexpr int KT = 2304;
    constexpr int NSTEP = 72;
    __shared__ __attribute__((aligned(16))) _Float16 L[49152];   // 96KB, 3 slots
    __shared__ float wred[8];

    const int t = threadIdx.x;
    const int wave = t >> 6, lane = t & 63;
    const int wm = wave >> 2;            // 0..1 : m-half (128 rows)
    const int wn = wave & 3;             // 0..3 : n-quarter (64 cols)
    const int fr = lane & 15, fq = lane >> 4;

    // bijective chunked XCD swizzle over 196 blocks (q=24, r=4; m204 form)
    const int orig = blockIdx.x;
    const int xcd = orig & 7, i8 = orig >> 3;
    const int wgid = (xcd < 4 ? xcd * 25 : 100 + (xcd - 4) * 24) + i8;
    const int n0 = wgid << 8;            // 256 pixels per block

    // ---- staging coords: this thread stages row srow, chunks {wm, wm+2}
    const int srow = wn * 64 + lane;     // note: wn==wave&3 spans 0..255 rows
    const char* aSrc = (const char*)Wq + (size_t)srow * (KT * 2);
    const int nb = n0 + srow;
    const int bb = nb / 784;
    const int rbp = nb - bb * 784;
    const int ohb = rbp / 28, owb = rbp - (rbp / 28) * 28;

    const char* bptr = (const char*)zp;
    auto stage = [&](int tt, int slot) {
        char* base = (char*)L + slot * 32768;
        if ((tt & 7) == 0) {             // new tap: recompute pixel base
            const int p = tt >> 3;
            const int kh = p / 3, kw = p - kh * 3;
            if constexpr (MODE == 0) {
                int ih = ohb * 2 - 1 + kh;
                int par = (kw == 1) ? 0 : 1;
                int j = (kw == 0) ? owb - 1 : owb;
                bool ok = ((unsigned)ih < 56u) && ((unsigned)j < 28u);
                bptr = ok ? (const char*)Xf + (((((size_t)bb * 56 + ih) * 2 + par) * 28 + j) << 9)
                          : (const char*)zp;
            } else {
                int ih = ohb - 1 + kh, iw = owb - 1 + kw;
                bool ok = ((unsigned)ih < 28u) && ((unsigned)iw < 28u);
                bptr = ok ? (const char*)Xf + ((((size_t)bb * 28 + ih) * 28 + iw) << 9)
                          : (const char*)zp;
            }
        }
        const size_t ka = (size_t)tt * 64;
        const int ko = (tt & 7) * 64;
        GLD16(aSrc + ka + wm * 16,          base + wm * 4096 + wn * 1024);
        GLD16(aSrc + ka + (2 + wm) * 16,    base + (2 + wm) * 4096 + wn * 1024);
        GLD16(bptr + ko + wm * 16,          base + 16384 + wm * 4096 + wn * 1024);
        GLD16(bptr + ko + (2 + wm) * 16,    base + 16384 + (2 + wm) * 4096 + wn * 1024);
    };

    f4 acc[8][4];
#pragma unroll
    for (int i = 0; i < 8; ++i)
#pragma unroll
        for (int j = 0; j < 4; ++j) acc[i][j] = f4{0.f, 0.f, 0.f, 0.f};

    stage(0, 0);
    stage(1, 1);
    int cs = 0, ns = 2;
#pragma unroll 1
    for (int it = 0; it < NSTEP - 1; ++it) {
        // gate: own outstanding = 8 (tiles it, it+1); release the oldest tile
        asm volatile("s_waitcnt vmcnt(4)" ::: "memory");
        __builtin_amdgcn_s_barrier();
        const _Float16* Sa = &L[cs * 16384];
        const _Float16* Sb = Sa + 8192;
        h8 af0[4], af1[4], bf[4];
#pragma unroll
        for (int i = 0; i < 4; ++i) {
            af0[i] = *(const h8*)&Sa[fq * 2048 + (wm * 128 + i * 16 + fr) * 8];
            bf[i]  = *(const h8*)&Sb[fq * 2048 + (wn * 64 + i * 16 + fr) * 8];
        }
#pragma unroll
        for (int i = 0; i < 4; ++i)
            af1[i] = *(const h8*)&Sa[fq * 2048 + (wm * 128 + 64 + i * 16 + fr) * 8];
        if (it + 2 < NSTEP) stage(it + 2, ns);
        __builtin_amdgcn_s_setprio(1);
#pragma unroll
        for (int mi = 0; mi < 4; ++mi)
#pragma unroll
            for (int ni = 0; ni < 4; ++ni)
                acc[mi][ni] = __builtin_amdgcn_mfma_f32_16x16x32_f16(af0[mi], bf[ni], acc[mi][ni], 0, 0, 0);
#pragma unroll
        for (int mi = 0; mi < 4; ++mi)
#pragma unroll
            for (int ni = 0; ni < 4; ++ni)
                acc[4 + mi][ni] = __builtin_amdgcn_mfma_f32_16x16x32_f16(af1[mi], bf[ni], acc[4 + mi][ni], 0, 0, 0);
        __builtin_amdgcn_s_setprio(0);
        cs = (cs == 2) ? 0 : cs + 1;
        ns = (ns == 2) ? 0 : ns + 1;
    }
    {   // peeled last iteration: drain everything once
        asm volatile("s_waitcnt vmcnt(0)" ::: "memory");
        __builtin_amdgcn_s_barrier();
        const _Float16* Sa = &L[cs * 16384];
        const _Float16* Sb = Sa + 8192;
        h8 af0[4], af1[4], bf[4];
#pragma unroll
        for (int i = 0; i < 4; ++i) {
            af0[i] = *(const h8*)&Sa[fq * 2048 + (wm * 128 + i * 16 + fr) * 8];
            bf[i]  = *(const h8*)&Sb[fq * 2048 + (wn * 64 + i * 16 + fr) * 8];
        }
#pragma unroll
        for (int i = 0; i < 4; ++i)
            af1[i] = *(const h8*)&Sa[fq * 2048 + (wm * 128 + 64 + i * 16 + fr) * 8];
#pragma unroll
        for (int mi = 0; mi < 4; ++mi)
#pragma unroll
            for (int ni = 0; ni < 4; ++ni)
                acc[mi][ni] = __builtin_amdgcn_mfma_f32_16x16x32_f16(af0[mi], bf[ni], acc[mi][ni], 0, 0, 0);
#pragma unroll
        for (int mi = 0; mi < 4; ++mi)
#pragma unroll
            for (int ni = 0; ni < 4; ++ni)
                acc[4 + mi][ni] = __builtin_amdgcn_mfma_f32_16x16x32_f16(af1[mi], bf[ni], acc[4 + mi][ni], 0, 0, 0);
    }

    // ---- epilogue: scale+bias+relu, write Y, block max -> spread slot
    float tmax = 0.f;
#pragma unroll
    for (int mi = 0; mi < 8; ++mi) {
        const int m = wm * 128 + mi * 16 + fq * 4;
        const f4 sc = *(const f4*)&scale[m];
        const f4 bi = *(const f4*)&bias[m];
#pragma unroll
        for (int ni = 0; ni < 4; ++ni) {
            const int n = n0 + wn * 64 + ni * 16 + fr;
            f4 v = acc[mi][ni] * sc + bi;
            f4 r;
            r.x = fmaxf(v.x, 0.f); r.y = fmaxf(v.y, 0.f);
            r.z = fmaxf(v.z, 0.f); r.w = fmaxf(v.w, 0.f);
            tmax = fmaxf(tmax, fmaxf(fmaxf(r.x, r.y), fmaxf(r.z, r.w)));
            *(f4*)&Y[(size_t)n * 256 + m] = r;
        }
    }
#pragma unroll
    for (int off = 32; off > 0; off >>= 1)
        tmax = fmaxf(tmax, __shfl_xor(tmax, off));
    if (lane == 0) wred[wave] = tmax;
    __syncthreads();
    if (t == 0) {
        float mx = 0.f;
#pragma unroll
        for (int i = 0; i < 8; ++i) mx = fmaxf(mx, wred[i]);
        atomicMax(&slots[(wgid & (NSLOT - 1)) * SLOTSTRIDE], __float_as_int(mx));
    }

    // ---- MODE 0: 1x1-s2 shortcut, register-direct (no LDS, no barriers)
    if constexpr (MODE == 0) {
        const char* pb[4];
#pragma unroll
        for (int ni = 0; ni < 4; ++ni) {
            int n = n0 + wn * 64 + ni * 16 + fr;
            int b2 = n / 784;
            int r2 = n - b2 * 784;
            int oh2 = r2 / 28, ow2 = r2 - (r2 / 28) * 28;
            pb[ni] = (const char*)Xf + (((((size_t)b2 * 56 + oh2 * 2) * 2 + 0) * 28 + ow2) << 9);
        }
#pragma unroll
        for (int i = 0; i < 8; ++i)
#pragma unroll
            for (int j = 0; j < 4; ++j) acc[i][j] = f4{0.f, 0.f, 0.f, 0.f};
#pragma unroll 1
        for (int st = 0; st < 8; ++st) {
            h8 sf[8], bg[4];
#pragma unroll
            for (int mi = 0; mi < 8; ++mi)
                sf[mi] = *(const h8*)((const char*)Wsc +
                         (size_t)(wm * 128 + mi * 16 + fr) * 512 + st * 64 + fq * 16);
#pragma unroll
            for (int ni = 0; ni < 4; ++ni)
                bg[ni] = *(const h8*)(pb[ni] + st * 64 + fq * 16);
#pragma unroll
            for (int mi = 0; mi < 8; ++mi)
#pragma unroll
                for (int ni = 0; ni < 4; ++ni)
                    acc[mi][ni] = __builtin_amdgcn_mfma_f32_16x16x32_f16(sf[mi], bg[ni], acc[mi][ni], 0, 0, 0);
        }
#pragma unroll
        for (int mi = 0; mi < 8; ++mi) {
            const int m = wm * 128 + mi * 16 + fq * 4;
            const f4 ssc = *(const f4*)&scale_sc[m];
#pragma unroll
            for (int ni = 0; ni < 4; ++ni) {
                const int n = n0 + wn * 64 + ni * 16 + fr;
                f4 s = acc[mi][ni] * ssc;
                *(f4*)&Ysc[(size_t)n * 256 + m] = s;
            }
        }
    }
}

// ---------------------------------------------------------------------------
__global__ void mid_k(const int* __restrict__ slotsA, const float* __restrict__ ws2,
                      const float* __restrict__ b2f, float* __restrict__ scale2,
                      float* __restrict__ bias2, float* __restrict__ a1p)
{
    const int o = threadIdx.x;
    const float a1 = fmaxf(slot_max(slotsA) / 1023.f, 1e-8f);
    const float s2 = ws2[o] * a1;
    float bq = fminf(fmaxf(rintf(b2f[o] / s2), -128.f), 127.f);
    scale2[o] = s2;
    bias2[o] = bq * s2;
    if (o == 0) a1p[0] = a1;
}

__global__ void quant_x2(const float* __restrict__ t1, const float* __restrict__ a1p,
                         _Float16* __restrict__ x2)
{
    const size_t i = (size_t)blockIdx.x * 256 + threadIdx.x;
    const float a1 = a1p[0];
    f4 v = ((const f4*)t1)[i];
    h4 o;
    o[0] = (_Float16)fminf(rintf(v.x / a1), 1023.f);
    o[1] = (_Float16)fminf(rintf(v.y / a1), 1023.f);
    o[2] = (_Float16)fminf(rintf(v.z / a1), 1023.f);
    o[3] = (_Float16)fminf(rintf(v.w / a1), 1023.f);
    ((h4*)x2)[i] = o;
}

__global__ void add_short_k(const float* __restrict__ t2, const float* __restrict__ sh,
                            const int* __restrict__ slotsB, int* __restrict__ slotsC,
                            float* __restrict__ o3)
{
    const float a2 = fmaxf(slot_max(slotsB) / 1023.f, 1e-8f);
    const float inv_a2 = 1.f / a2;
    float tmax = 0.f;
    const size_t base = (size_t)blockIdx.x * 256 + threadIdx.x;
#pragma unroll
    for (int it = 0; it < 4; ++it) {
        const size_t i = base + (size_t)it * 802816;   // 3136*256
        f4 v = ((const f4*)t2)[i];
        f4 s = ((const f4*)sh)[i];
        f4 r;
        r.x = fmaxf(fminf(rintf(v.x * inv_a2), 1023.f) * a2 + s.x, 0.f);
        r.y = fmaxf(fminf(rintf(v.y * inv_a2), 1023.f) * a2 + s.y, 0.f);
        r.z = fmaxf(fminf(rintf(v.z * inv_a2), 1023.f) * a2 + s.z, 0.f);
        r.w = fmaxf(fminf(rintf(v.w * inv_a2), 1023.f) * a2 + s.w, 0.f);
        ((f4*)o3)[i] = r;
        tmax = fmaxf(tmax, fmaxf(fmaxf(r.x, r.y), fmaxf(r.z, r.w)));
    }
#pragma unroll
    for (int off = 32; off > 0; off >>= 1)
        tmax = fmaxf(tmax, __shfl_xor(tmax, off));
    __shared__ float wred[4];
    if ((threadIdx.x & 63) == 0) wred[threadIdx.x >> 6] = tmax;
    __syncthreads();
    if (threadIdx.x == 0) {
        float mx = fmaxf(fmaxf(wred[0], wred[1]), fmaxf(wred[2], wred[3]));
        atomicMax(&slotsC[(blockIdx.x & (NSLOT - 1)) * SLOTSTRIDE], __float_as_int(mx));
    }
}

__global__ void finalize_k(const float* __restrict__ o3, const int* __restrict__ slotsC,
                           float* __restrict__ dout, int out_size)
{
    const int b = blockIdx.x / 28, oh = blockIdx.x - (blockIdx.x / 28) * 28;
    const float a3 = fmaxf(slot_max(slotsC) / 1023.f, 1e-8f);
    __shared__ float tile[28 * 257];
    const float* src = o3 + (size_t)(b * 28 + oh) * 28 * 256;
    for (int i = threadIdx.x; i < 7168; i += 256)
        tile[(i >> 8) * 257 + (i & 255)] = src[i];
    __syncthreads();
    for (int j = threadIdx.x; j < 7168; j += 256) {
        int c = j / 28, ww = j - (j / 28) * 28;
        float v = tile[ww * 257 + c];
        float q = fminf(rintf(v / a3), 1023.f);
        dout[(((size_t)b * 256 + c) * 28 + oh) * 28 + ww] = q * a3;
    }
    if (blockIdx.x == 0 && threadIdx.x == 0) dout[(size_t)out_size - 1] = a3;
}

// ---------------------------------------------------------------------------
extern "C" void kernel_launch(void* const* d_in, const int* in_sizes, int n_in,
                              void* d_out, int out_size, void* d_ws, size_t ws_size,
                              hipStream_t stream)
{
    const float* x   = (const float*)d_in[0];
    const float* as_ = (const float*)d_in[1];
    const float* wsc = (const float*)d_in[2];
    const float* w1  = (const float*)d_in[3];
    const float* g1  = (const float*)d_in[4];
    const float* b1  = (const float*)d_in[5];
    const float* m1  = (const float*)d_in[6];
    const float* v1  = (const float*)d_in[7];
    const float* w2  = (const float*)d_in[8];
    const float* g2  = (const float*)d_in[9];
    const float* b2  = (const float*)d_in[10];
    const float* m2  = (const float*)d_in[11];
    const float* v2  = (const float*)d_in[12];
    float* out = (float*)d_out;

    char* w = (char*)d_ws;
    size_t off = 0;
    auto alloc = [&](size_t bytes) { size_t c = off; off += (bytes + 255) & ~(size_t)255; return c; };
    const size_t oXF = alloc((size_t)64 * 56 * 56 * 256 * 2);  // parity NHWC fp16 hi/lo
    const size_t oY1 = alloc((size_t)NEL * 4);                 // t1 / o3
    const size_t oSH = alloc((size_t)NEL * 4);                 // shortcut
    const size_t oX2 = alloc((size_t)NEL * 2);                 // x2 fp16
    const size_t oW1 = alloc((size_t)256 * 2304 * 2);
    const size_t oW2 = alloc((size_t)256 * 2304 * 2);
    const size_t oWS = alloc((size_t)256 * 256 * 2);
    const size_t oSC = alloc((size_t)8 * 256 * 4);
    const size_t oMS = alloc(3 * NSLOT * SLOTSTRIDE * 4 + 2048);
    if (off > ws_size) {
        fprintf(stderr, "kernel_launch: ws too small: need %zu have %zu\n", off, ws_size);
        return;
    }

    _Float16* xf   = (_Float16*)(w + oXF);
    float*    y1   = (float*)(w + oY1);
    float*    sh   = (float*)(w + oSH);
    _Float16* x2   = (_Float16*)(w + oX2);
    _Float16* wq1  = (_Float16*)(w + oW1);
    _Float16* wq2  = (_Float16*)(w + oW2);
    _Float16* wscd = (_Float16*)(w + oWS);
    float* scl = (float*)(w + oSC);
    float *scale1 = scl, *bias1 = scl + 256, *scale_sc = scl + 512, *ws2 = scl + 768,
          *b2f = scl + 1024, *scale2 = scl + 1280, *bias2 = scl + 1536, *a1p = scl + 1792;
    int* slots  = (int*)(w + oMS);
    int* slotsA = slots;
    int* slotsB = slots + NSLOT * SLOTSTRIDE;
    int* slotsC = slots + 2 * NSLOT * SLOTSTRIDE;
    _Float16* zp = (_Float16*)(w + oMS + 3 * NSLOT * SLOTSTRIDE * 4);
    float* y2 = (float*)(w + oXF);   // reuse xf region (dead after conv1)
    float* o3 = (float*)(w + oY1);   // reuse t1 region (dead after quant_x2)

    init_ws<<<1, 256, 0, stream>>>(slots, zp);
    prep_wsc<<<256, 256, 0, stream>>>(wsc, as_, wscd, scale_sc);
    prep_w1<<<256, 256, 0, stream>>>(w1, g1, b1, m1, v1, as_, wq1, scale1, bias1);
    prep_w2<<<256, 256, 0, stream>>>(w2, g2, b2, m2, v2, wq2, ws2, b2f);
    prep_x<<<64 * 56, 256, 0, stream>>>(x, as_, xf);
    conv_k<0><<<196, 512, 0, stream>>>(xf, wq1, wscd, scale1, bias1, scale_sc,
                                       y1, sh, slotsA, zp);
    mid_k<<<1, 256, 0, stream>>>(slotsA, ws2, b2f, scale2, bias2, a1p);
    quant_x2<<<12544, 256, 0, stream>>>(y1, a1p, x2);
    conv_k<1><<<196, 512, 0, stream>>>(x2, wq2, nullptr, scale2, bias2, nullptr,
                                       y2, nullptr, slotsB, zp);
    add_short_k<<<3136, 256, 0, stream>>>(y2, sh, slotsB, slotsC, o3);
    finalize_k<<<64 * 28, 256, 0, stream>>>(o3, slotsC, out, out_size);
}